// Round 4
// baseline (333.652 us; speedup 1.0000x reference)
//
#include <hip/hip_runtime.h>

typedef unsigned short u16;
typedef unsigned int u32;

#define D_DIM 128
#define CHUNK 4096    // elements scanned per block (256 threads x 16)
#define SCHUNK 4096   // edges per scatter stripe
#define NPART 8       // XCD count

typedef __attribute__((ext_vector_type(8))) short bf16x8;
typedef __attribute__((ext_vector_type(4))) float f32x4;

__device__ __forceinline__ float bf2f(u16 h) {
    u32 u = ((u32)h) << 16;
    return __uint_as_float(u);
}
__device__ __forceinline__ u16 f2bf(float f) {
    u32 u = __float_as_uint(f);
    u32 r = (u >> 16) & 1u;
    u += 0x7fffu + r;                 // round-to-nearest-even
    return (u16)(u >> 16);
}
__device__ __forceinline__ float lo16(u32 u) { return bf2f((u16)(u & 0xffffu)); }
__device__ __forceinline__ float hi16(u32 u) { return bf2f((u16)(u >> 16)); }

// --- K1: zero scratch words + dtype detect (merged; harness symbol kept) ----
__global__ void GCNLayer_76647986365164_kernel(int* p, int nwords,
                                               const u32* w, int* flag) {
    int i = blockIdx.x * blockDim.x + threadIdx.x;
    if (i < nwords) p[i] = 0;
    if (blockIdx.x == 0) {
        __shared__ int cnt;
        if (threadIdx.x == 0) cnt = 0;
        __syncthreads();
        int c = 0;
        for (int j = 0; j < 4; ++j) {
            u32 x = w[threadIdx.x * 4 + j];
            u32 e = (x >> 7) & 0xFFu;
            if (e >= 100u && e <= 140u) c++;
        }
        atomicAdd(&cnt, c);
        __syncthreads();
        if (threadIdx.x == 0) flag[0] = (cnt >= 700) ? 1 : 0;
    }
}

// --- K1b: fp32 feature -> bf16 copy, and (last block) W prepack -------------
// W prepack: fragment-order bf16 planes (hi + residual-lo) so k_gemm staging
// is a pure coalesced memcpy with ZERO conversion VALU and ONE barrier.
// R3 evidence: k_gemm at 52us with MfmaUtil 4.5%/VALU 22%/occ 29% -- each of
// 1563 blocks re-read + re-converted W twice behind 3 barriers (latency-bound).
__global__ void k_tobf(const float* __restrict__ f, u16* __restrict__ fb,
                       const void* __restrict__ W, u16* __restrict__ wpre,
                       const int* __restrict__ flag, int total8) {
    const int bf = flag[0];
    if (blockIdx.x == gridDim.x - 1) {          // W prepack block
        const int tid = threadIdx.x;
        #pragma unroll
        for (int i = 0; i < 8; ++i) {
            int idx = i * 256 + tid;            // 2048 fragment units
            int frag = idx >> 6, dl = idx & 63;
            int ot = frag >> 2, kt = frag & 3;
            int dg = dl >> 4, dc = dl & 15;
            int row = ot * 16 + dc, col = kt * 32 + dg * 8;
            if (bf) {
                *(uint4*)(wpre + (size_t)idx * 8) =
                    *(const uint4*)((const u16*)W + row * 128 + col);
            } else {
                const float* Wf = (const float*)W;
                float4 x = *(const float4*)(Wf + row * 128 + col);
                float4 y = *(const float4*)(Wf + row * 128 + col + 4);
                float v[8] = {x.x, x.y, x.z, x.w, y.x, y.y, y.z, y.w};
                u16 h0[8], h1[8];
                #pragma unroll
                for (int j = 0; j < 8; ++j) {
                    h0[j] = f2bf(v[j]);
                    h1[j] = f2bf(v[j] - bf2f(h0[j]));   // residual plane
                }
                uint4 p0, p1;
                p0.x = (u32)h0[0] | ((u32)h0[1] << 16);
                p0.y = (u32)h0[2] | ((u32)h0[3] << 16);
                p0.z = (u32)h0[4] | ((u32)h0[5] << 16);
                p0.w = (u32)h0[6] | ((u32)h0[7] << 16);
                p1.x = (u32)h1[0] | ((u32)h1[1] << 16);
                p1.y = (u32)h1[2] | ((u32)h1[3] << 16);
                p1.z = (u32)h1[4] | ((u32)h1[5] << 16);
                p1.w = (u32)h1[6] | ((u32)h1[7] << 16);
                *(uint4*)(wpre + (size_t)idx * 8) = p0;
                *(uint4*)(wpre + 16384 + (size_t)idx * 8) = p1;
            }
        }
        return;
    }
    if (bf) return;                  // input already bf16, no feature copy
    int i = blockIdx.x * 256 + threadIdx.x;
    if (i >= total8) return;
    float4 a = ((const float4*)f)[i * 2];
    float4 b = ((const float4*)f)[i * 2 + 1];
    uint4 o;
    o.x = (u32)f2bf(a.x) | ((u32)f2bf(a.y) << 16);
    o.y = (u32)f2bf(a.z) | ((u32)f2bf(a.w) << 16);
    o.z = (u32)f2bf(b.x) | ((u32)f2bf(b.y) << 16);
    o.w = (u32)f2bf(b.z) | ((u32)f2bf(b.w) << 16);
    ((uint4*)fb)[i] = o;
}

// --- K2: in-degree count + per-edge bucket rank -----------------------------
__global__ void k_deg(const int* __restrict__ dst, int* __restrict__ deg,
                      int* __restrict__ rank, int E) {
    int i = blockIdx.x * blockDim.x + threadIdx.x;
    if (i < E) rank[i] = atomicAdd(&deg[dst[i]], 1);
}

// --- K3a: block-local exclusive scan (multi-block; LDS Hillis-Steele) -------
__global__ void k_scan_local(const int* deg, int* offs, int* bsums, int n) {
    __shared__ int tsum[256];
    const int tid = threadIdx.x;
    const int base = blockIdx.x * CHUNK + tid * 16;
    int v[16];
    int run = 0;
    for (int j = 0; j < 16; ++j) {
        int idx = base + j;
        v[j] = (idx < n) ? deg[idx] : 0;
        run += v[j];
    }
    tsum[tid] = run;
    __syncthreads();
    for (int off = 1; off < 256; off <<= 1) {      // inclusive scan of thread sums
        int val = tsum[tid];
        int add = (tid >= off) ? tsum[tid - off] : 0;
        __syncthreads();
        tsum[tid] = val + add;
        __syncthreads();
    }
    int acc = tsum[tid] - run;                     // exclusive start (local)
    for (int j = 0; j < 16; ++j) {
        int idx = base + j;
        if (idx < n) offs[idx] = acc;
        acc += v[j];
    }
    if (tid == 255) bsums[blockIdx.x] = tsum[255];
}

// --- K3b: add scanned block totals; emit final offs -------------------------
__global__ void k_scan_add(int* offs, const int* bsums, int n, int nblk) {
    __shared__ int carry_s;
    const int tid = threadIdx.x;
    const int b = blockIdx.x;
    if (tid == 0) {
        int c = 0;
        for (int i = 0; i < b; ++i) c += bsums[i];
        carry_s = c;
        if (b == nblk - 1) offs[n] = c + bsums[b];   // total == E
    }
    __syncthreads();
    const int carry = carry_s;
    const int base = b * CHUNK + tid * 16;
    for (int j = 0; j < 16; ++j) {
        int idx = base + j;
        if (idx < n) offs[idx] += carry;
    }
}

// --- K4: scatter edges into CSR buckets, XCD-partitioned, atomic-free -------
__global__ void k_scatter(const int* __restrict__ src, const int* __restrict__ dst,
                          const int* __restrict__ rank, const int* __restrict__ offs,
                          int* __restrict__ csr, int E, int nper) {
    const int pr = blockIdx.x & (NPART - 1);
    const int s  = blockIdx.x >> 3;
    const int lo = pr * nper;
    const int hi = lo + nper;
    const int base = s * SCHUNK;
    int end = base + SCHUNK;
    if (end > E) end = E;
    for (int i = base + (int)threadIdx.x; i < end; i += 256) {
        int d = dst[i];
        if (d >= lo && d < hi) {
            csr[offs[d] + rank[i]] = src[i];
        }
    }
}

// --- K5: gather-reduce mean aggregation, one wave per node ------------------
// Gathers bf16 rows (256B): original buffer when input is bf16, the k_tobf
// copy otherwise. 16B/lane, 4 rows per load instruction, shfl-combine.
__global__ void k_aggregate(const void* feature, const u16* __restrict__ fcopy,
                            const int* offs, const int* csr, u16* agg,
                            const int* flag, int n, int npad) {
    int node = blockIdx.x * 4 + (threadIdx.x >> 6);
    int lane = threadIdx.x & 63;
    if (node >= npad) return;
    const int g = lane >> 4;       // edge sub-slot 0..3
    const int c = lane & 15;       // 16B chunk (8 bf16 cols) within row
    const u16* fb = flag[0] ? (const u16*)feature : fcopy;
    float acc[8];
    #pragma unroll
    for (int t = 0; t < 8; ++t) acc[t] = 0.f;
    int degn = 0;
    if (node < n) {
        int s = offs[node], e = offs[node + 1];
        degn = e - s;
        const uint4* fq = (const uint4*)fb;   // row = 16 uint4
        for (int j = s; j < e; j += 16) {
            int j0 = j + g, j1 = j0 + 4, j2 = j0 + 8, j3 = j0 + 12;
            uint4 u0 = {0,0,0,0}, u1 = {0,0,0,0}, u2 = {0,0,0,0}, u3 = {0,0,0,0};
            if (j0 < e) u0 = fq[(size_t)csr[j0] * 16 + c];
            if (j1 < e) u1 = fq[(size_t)csr[j1] * 16 + c];
            if (j2 < e) u2 = fq[(size_t)csr[j2] * 16 + c];
            if (j3 < e) u3 = fq[(size_t)csr[j3] * 16 + c];
            #define ACC8(U) \
                acc[0] += lo16(U.x); acc[1] += hi16(U.x); \
                acc[2] += lo16(U.y); acc[3] += hi16(U.y); \
                acc[4] += lo16(U.z); acc[5] += hi16(U.z); \
                acc[6] += lo16(U.w); acc[7] += hi16(U.w);
            ACC8(u0); ACC8(u1); ACC8(u2); ACC8(u3);
            #undef ACC8
        }
    }
    // combine the 4 edge-slot partials (lanes g=0..3 share chunk c)
    #pragma unroll
    for (int t = 0; t < 8; ++t) {
        acc[t] += __shfl_xor(acc[t], 16);
        acc[t] += __shfl_xor(acc[t], 32);
    }
    float sc = 1.0f / (float)(degn > 1 ? degn : 1);
    if (g == 0) {
        uint4 o4;
        o4.x = (u32)f2bf(acc[0] * sc) | ((u32)f2bf(acc[1] * sc) << 16);
        o4.y = (u32)f2bf(acc[2] * sc) | ((u32)f2bf(acc[3] * sc) << 16);
        o4.z = (u32)f2bf(acc[4] * sc) | ((u32)f2bf(acc[5] * sc) << 16);
        o4.w = (u32)f2bf(acc[6] * sc) | ((u32)f2bf(acc[7] * sc) << 16);
        ((uint4*)(agg + (size_t)node * D_DIM))[c] = o4;
    }
}

// --- K6: h = agg @ W^T + b via bf16 MFMA, prepacked W, h in place -----------
// 128 rows/block, 8 waves (512 thr), wave w owns rows rb+w*16..+15.
// W staged ONCE from the prepacked fragment-order planes (coalesced memcpy,
// zero conversion VALU, one barrier). LDS = exactly 64KB (both planes) ->
// 2 blocks/CU with launch_bounds(512,4) = 50% occupancy (R3 was 29% with a
// 3-barrier dual-restage structure). BN partials: per-wave coalesced global
// rows, NO atomics anywhere.
__global__ __launch_bounds__(512, 4)
void k_gemm(u16* __restrict__ agg, const u16* __restrict__ wpre,
            const void* __restrict__ bias, float* __restrict__ parts,
            const int* __restrict__ flag, int n) {
    __shared__ u16 sW[2 * 2048 * 8];          // 64 KB: plane0 | plane1
    const int tid = threadIdx.x;
    const int rb = blockIdx.x * 128;
    const int bf = flag[0];
    const int w = tid >> 6;
    const int lane = tid & 63;
    const int g = lane >> 4, c = lane & 15;

    // stage plane0 (+ plane1 if fp32 path): pure coalesced uint4 copy
    #pragma unroll
    for (int i = 0; i < 4; ++i) {
        int idx = i * 512 + tid;
        *(uint4*)(&sW[idx * 8]) = *(const uint4*)(wpre + (size_t)idx * 8);
    }
    if (!bf) {
        #pragma unroll
        for (int i = 0; i < 4; ++i) {
            int idx = i * 512 + tid;
            *(uint4*)(&sW[16384 + idx * 8]) =
                *(const uint4*)(wpre + 16384 + (size_t)idx * 8);
        }
    }

    // A fragments: 4 x 16B per lane, from global (rows written by k_aggregate)
    bf16x8 afr[4];
    {
        const u16* arow = agg + (size_t)(rb + w * 16 + c) * D_DIM + g * 8;
        #pragma unroll
        for (int kt = 0; kt < 4; ++kt)
            afr[kt] = *(const bf16x8*)(arow + kt * 32);
    }

    f32x4 acc[8];
    #pragma unroll
    for (int ot = 0; ot < 8; ++ot) acc[ot] = (f32x4){0.f, 0.f, 0.f, 0.f};

    __syncthreads();
    #pragma unroll
    for (int ot = 0; ot < 8; ++ot) {
        #pragma unroll
        for (int kt = 0; kt < 4; ++kt) {
            bf16x8 bfr = *(const bf16x8*)(&sW[((ot * 4 + kt) * 64 + lane) * 8]);
            acc[ot] = __builtin_amdgcn_mfma_f32_16x16x32_bf16(
                afr[kt], bfr, acc[ot], 0, 0, 0);
        }
    }
    if (!bf) {                                 // residual plane, same acc
        #pragma unroll
        for (int ot = 0; ot < 8; ++ot) {
            #pragma unroll
            for (int kt = 0; kt < 4; ++kt) {
                bf16x8 bfr = *(const bf16x8*)(
                    &sW[16384 + ((ot * 4 + kt) * 64 + lane) * 8]);
                acc[ot] = __builtin_amdgcn_mfma_f32_16x16x32_bf16(
                    afr[kt], bfr, acc[ot], 0, 0, 0);
            }
        }
    }

    // Epilogue: bias, BN partials (rows<n only), packed bf16 store.
    // D layout: col = ot*16 + c, row = rowbase + r.
    const int rowbase = rb + w * 16 + g * 4;
    float* wrow = parts + ((size_t)blockIdx.x * 8 + w) * 256;
    #pragma unroll
    for (int ot = 0; ot < 8; ++ot) {
        const int o = ot * 16 + c;
        float bv = bf ? bf2f(((const u16*)bias)[o]) : ((const float*)bias)[o];
        float s = 0.f, q = 0.f;
        float hv[4];
        #pragma unroll
        for (int r = 0; r < 4; ++r) {
            float h = acc[ot][r] + bv;
            hv[r] = h;
            if (rowbase + r < n) { s += h; q += h * h; }
        }
        #pragma unroll
        for (int r = 0; r < 4; ++r) {
            float hp = __shfl_xor(hv[r], 1);       // neighbor col (o^1)
            if (!(lane & 1)) {
                u32 pk = (u32)f2bf(hv[r]) | ((u32)f2bf(hp) << 16);
                *(u32*)(agg + (size_t)(rowbase + r) * D_DIM + o) = pk;
            }
        }
        s += __shfl_xor(s, 16); s += __shfl_xor(s, 32);
        q += __shfl_xor(q, 16); q += __shfl_xor(q, 32);
        if (g == 0) { wrow[o] = s; wrow[128 + o] = q; }   // coalesced 64B runs
    }
}

// --- K6b: reduce per-wave BN partials into stats (8K atomics total) ---------
__global__ void k_redstats(const float* __restrict__ partials,
                           float* __restrict__ stats, int nb) {
    const int tid = threadIdx.x;
    float acc = 0.f;
    for (int r = blockIdx.x; r < nb; r += gridDim.x)
        acc += partials[(size_t)r * 256 + tid];
    atomicAdd(&stats[tid], acc);
}

// --- K8: out = feature + relu(h*scale + shift); BN finalize folded in -------
__global__ void k_apply(const u16* h, const void* feature, const float* stats,
                        const void* gamma, const void* beta, void* outp,
                        const int* flag, int total8, float invn) {
    __shared__ float ssc[128], ssh[128];
    int tid = threadIdx.x;
    int bf = flag[0];
    if (tid < 128) {
        float mean = stats[tid] * invn;
        float var = stats[128 + tid] * invn - mean * mean;
        var = fmaxf(var, 0.f);
        float inv = rsqrtf(var + 1e-5f);
        float g = bf ? bf2f(((const u16*)gamma)[tid]) : ((const float*)gamma)[tid];
        float bb = bf ? bf2f(((const u16*)beta)[tid]) : ((const float*)beta)[tid];
        float sc = inv * g;
        ssc[tid] = sc;
        ssh[tid] = bb - mean * sc;
    }
    __syncthreads();
    int i = blockIdx.x * 256 + tid;
    if (i >= total8) return;
    size_t base = (size_t)i * 8;
    int c0 = (int)(base & (D_DIM - 1));
    uint4 h4 = ((const uint4*)h)[i];
    u32 hw[4] = {h4.x, h4.y, h4.z, h4.w};
    float hv[8];
    for (int j = 0; j < 4; ++j) { hv[2*j] = lo16(hw[j]); hv[2*j+1] = hi16(hw[j]); }
    float fv[8];
    if (bf) {
        uint4 f4 = ((const uint4*)feature)[i];
        u32 fw[4] = {f4.x, f4.y, f4.z, f4.w};
        for (int j = 0; j < 4; ++j) { fv[2*j] = lo16(fw[j]); fv[2*j+1] = hi16(fw[j]); }
    } else {
        float4 fa = ((const float4*)feature)[i * 2];
        float4 fb = ((const float4*)feature)[i * 2 + 1];
        fv[0]=fa.x; fv[1]=fa.y; fv[2]=fa.z; fv[3]=fa.w;
        fv[4]=fb.x; fv[5]=fb.y; fv[6]=fb.z; fv[7]=fb.w;
    }
    float ov[8];
    for (int j = 0; j < 8; ++j)
        ov[j] = fmaxf(hv[j] * ssc[c0 + j] + ssh[c0 + j], 0.f) + fv[j];
    if (bf) {
        uint4 o4;
        u32 ow[4];
        for (int j = 0; j < 4; ++j)
            ow[j] = (u32)f2bf(ov[2*j]) | ((u32)f2bf(ov[2*j+1]) << 16);
        o4.x = ow[0]; o4.y = ow[1]; o4.z = ow[2]; o4.w = ow[3];
        ((uint4*)outp)[i] = o4;
    } else {
        float4 oa, ob;
        oa.x=ov[0]; oa.y=ov[1]; oa.z=ov[2]; oa.w=ov[3];
        ob.x=ov[4]; ob.y=ov[5]; ob.z=ov[6]; ob.w=ov[7];
        ((float4*)outp)[i * 2] = oa;
        ((float4*)outp)[i * 2 + 1] = ob;
    }
}

static inline size_t al256s(size_t x) { return (x + 255) & ~(size_t)255; }
static inline int gmax1(int x) { return x > 0 ? x : 1; }

extern "C" void kernel_launch(void* const* d_in, const int* in_sizes, int n_in,
                              void* d_out, int out_size, void* d_ws, size_t ws_size,
                              hipStream_t stream) {
    const void* feature = d_in[0];
    const int*  src     = (const int*)d_in[1];
    const int*  dst     = (const int*)d_in[2];
    const void* W       = d_in[3];
    const void* bias    = d_in[4];
    const void* gamma   = d_in[5];
    const void* beta    = d_in[6];

    const int N = in_sizes[0] / D_DIM;
    const int E = in_sizes[1];
    const int Npad = (N + 127) & ~127;             // 128-row gemm blocks
    const int nblk = (N + CHUNK - 1) / CHUNK;      // scan blocks
    const int nper = (N + NPART - 1) / NPART;      // nodes per XCD partition
    const int gb   = Npad / 128;                   // gemm blocks
    const int nbp  = gb * 8;                       // partial rows (per wave)

    char* p = (char*)d_ws;
    size_t o = 0;
    int*   flag   = (int*)(p + o);      o += 256;
    int*   deg    = (int*)(p + o);      o += (size_t)N * 4;
    float* stats  = (float*)(p + o);    o += 256 * 4;           // sum[128],sq[128]
    const int zero_words = N + 256;                              // deg+stats contiguous
    o = al256s(o);
    u16*   wpre   = (u16*)(p + o);      o += al256s(2 * 16384 * 2);  // 2 bf16 planes
    int*   bsums  = (int*)(p + o);      o += al256s(((size_t)nblk + 8) * 4);
    int*   offs   = (int*)(p + o);      o += al256s(((size_t)N + 8) * 4);
    int*   csr    = (int*)(p + o);      o += al256s((size_t)E * 4);
    float* parts  = (float*)(p + o);    o += al256s((size_t)nbp * 256 * 4);
    u16*   agg    = (u16*)(p + o);      o += al256s((size_t)Npad * D_DIM * 2);
    int*   rank   = (int*)agg;   // aliased: rank (E ints) dies before k_aggregate
                                 // writes agg; Npad*256B >= E*4B here
    u16*   fbf    = (u16*)d_out; // bf16 feature copy; dead before k_apply writes
    (void)ws_size; (void)n_in; (void)out_size;

    int eb = gmax1((E + 255) / 256);
    int total8 = N * D_DIM / 8;
    int sblocks = gmax1(((E + SCHUNK - 1) / SCHUNK) * NPART);

    GCNLayer_76647986365164_kernel<<<gmax1((zero_words + 255) / 256), 256, 0, stream>>>(
        deg, zero_words, (const u32*)feature, flag);
    k_tobf<<<gmax1((total8 + 255) / 256) + 1, 256, 0, stream>>>(
        (const float*)feature, fbf, W, wpre, flag, total8);
    k_deg<<<eb, 256, 0, stream>>>(dst, deg, rank, E);
    k_scan_local<<<gmax1(nblk), 256, 0, stream>>>(deg, offs, bsums, N);
    k_scan_add<<<gmax1(nblk), 256, 0, stream>>>(offs, bsums, N, nblk);
    k_scatter<<<sblocks, 256, 0, stream>>>(src, dst, rank, offs, csr, E, nper);
    k_aggregate<<<gmax1(Npad / 4), 256, 0, stream>>>(
        feature, fbf, offs, csr, agg, flag, N, Npad);
    k_gemm<<<gmax1(gb), 512, 0, stream>>>(agg, wpre, bias, parts, flag, N);
    k_redstats<<<32, 256, 0, stream>>>(parts, stats, nbp);
    k_apply<<<gmax1((total8 + 255) / 256), 256, 0, stream>>>(
        agg, feature, stats, gamma, beta, d_out, flag, total8, 1.0f / (float)N);
}

// Round 5
// 294.772 us; speedup vs baseline: 1.1319x; 1.1319x over previous
//
#include <hip/hip_runtime.h>

typedef unsigned short u16;
typedef unsigned int u32;

#define D_DIM 128
#define CHUNK 4096    // elements scanned per block (256 threads x 16)
#define SCHUNK 4096   // edges per scatter stripe
#define NPART 8       // XCD count

typedef __attribute__((ext_vector_type(8))) short bf16x8;
typedef __attribute__((ext_vector_type(4))) float f32x4;

__device__ __forceinline__ float bf2f(u16 h) {
    u32 u = ((u32)h) << 16;
    return __uint_as_float(u);
}
__device__ __forceinline__ u16 f2bf(float f) {
    u32 u = __float_as_uint(f);
    u32 r = (u >> 16) & 1u;
    u += 0x7fffu + r;                 // round-to-nearest-even
    return (u16)(u >> 16);
}
__device__ __forceinline__ float lo16(u32 u) { return bf2f((u16)(u & 0xffffu)); }
__device__ __forceinline__ float hi16(u32 u) { return bf2f((u16)(u >> 16)); }

// --- K1: zero scratch words + dtype detect (merged; harness symbol kept) ----
__global__ void GCNLayer_76647986365164_kernel(int* p, int nwords,
                                               const u32* w, int* flag) {
    int i = blockIdx.x * blockDim.x + threadIdx.x;
    if (i < nwords) p[i] = 0;
    if (blockIdx.x == 0) {
        __shared__ int cnt;
        if (threadIdx.x == 0) cnt = 0;
        __syncthreads();
        int c = 0;
        for (int j = 0; j < 4; ++j) {
            u32 x = w[threadIdx.x * 4 + j];
            u32 e = (x >> 7) & 0xFFu;
            if (e >= 100u && e <= 140u) c++;
        }
        atomicAdd(&cnt, c);
        __syncthreads();
        if (threadIdx.x == 0) flag[0] = (cnt >= 700) ? 1 : 0;
    }
}

// --- K1b: fp32 feature -> bf16 copy, and (last block) W prepack -------------
// W prepack: fragment-order bf16 planes (hi + residual-lo) so k_gemm staging
// is a pure coalesced memcpy with ZERO conversion VALU and ONE barrier.
__global__ void k_tobf(const float* __restrict__ f, u16* __restrict__ fb,
                       const void* __restrict__ W, u16* __restrict__ wpre,
                       const int* __restrict__ flag, int total8) {
    const int bf = flag[0];
    if (blockIdx.x == gridDim.x - 1) {          // W prepack block
        const int tid = threadIdx.x;
        #pragma unroll
        for (int i = 0; i < 8; ++i) {
            int idx = i * 256 + tid;            // 2048 fragment units
            int frag = idx >> 6, dl = idx & 63;
            int ot = frag >> 2, kt = frag & 3;
            int dg = dl >> 4, dc = dl & 15;
            int row = ot * 16 + dc, col = kt * 32 + dg * 8;
            if (bf) {
                *(uint4*)(wpre + (size_t)idx * 8) =
                    *(const uint4*)((const u16*)W + row * 128 + col);
            } else {
                const float* Wf = (const float*)W;
                float4 x = *(const float4*)(Wf + row * 128 + col);
                float4 y = *(const float4*)(Wf + row * 128 + col + 4);
                float v[8] = {x.x, x.y, x.z, x.w, y.x, y.y, y.z, y.w};
                u16 h0[8], h1[8];
                #pragma unroll
                for (int j = 0; j < 8; ++j) {
                    h0[j] = f2bf(v[j]);
                    h1[j] = f2bf(v[j] - bf2f(h0[j]));   // residual plane
                }
                uint4 p0, p1;
                p0.x = (u32)h0[0] | ((u32)h0[1] << 16);
                p0.y = (u32)h0[2] | ((u32)h0[3] << 16);
                p0.z = (u32)h0[4] | ((u32)h0[5] << 16);
                p0.w = (u32)h0[6] | ((u32)h0[7] << 16);
                p1.x = (u32)h1[0] | ((u32)h1[1] << 16);
                p1.y = (u32)h1[2] | ((u32)h1[3] << 16);
                p1.z = (u32)h1[4] | ((u32)h1[5] << 16);
                p1.w = (u32)h1[6] | ((u32)h1[7] << 16);
                *(uint4*)(wpre + (size_t)idx * 8) = p0;
                *(uint4*)(wpre + 16384 + (size_t)idx * 8) = p1;
            }
        }
        return;
    }
    if (bf) return;                  // input already bf16, no feature copy
    int i = blockIdx.x * 256 + threadIdx.x;
    if (i >= total8) return;
    float4 a = ((const float4*)f)[i * 2];
    float4 b = ((const float4*)f)[i * 2 + 1];
    uint4 o;
    o.x = (u32)f2bf(a.x) | ((u32)f2bf(a.y) << 16);
    o.y = (u32)f2bf(a.z) | ((u32)f2bf(a.w) << 16);
    o.z = (u32)f2bf(b.x) | ((u32)f2bf(b.y) << 16);
    o.w = (u32)f2bf(b.z) | ((u32)f2bf(b.w) << 16);
    ((uint4*)fb)[i] = o;
}

// --- K2: in-degree count + per-edge bucket rank -----------------------------
__global__ void k_deg(const int* __restrict__ dst, int* __restrict__ deg,
                      int* __restrict__ rank, int E) {
    int i = blockIdx.x * blockDim.x + threadIdx.x;
    if (i < E) rank[i] = atomicAdd(&deg[dst[i]], 1);
}

// --- K3a: block-local exclusive scan (multi-block; LDS Hillis-Steele) -------
__global__ void k_scan_local(const int* deg, int* offs, int* bsums, int n) {
    __shared__ int tsum[256];
    const int tid = threadIdx.x;
    const int base = blockIdx.x * CHUNK + tid * 16;
    int v[16];
    int run = 0;
    for (int j = 0; j < 16; ++j) {
        int idx = base + j;
        v[j] = (idx < n) ? deg[idx] : 0;
        run += v[j];
    }
    tsum[tid] = run;
    __syncthreads();
    for (int off = 1; off < 256; off <<= 1) {      // inclusive scan of thread sums
        int val = tsum[tid];
        int add = (tid >= off) ? tsum[tid - off] : 0;
        __syncthreads();
        tsum[tid] = val + add;
        __syncthreads();
    }
    int acc = tsum[tid] - run;                     // exclusive start (local)
    for (int j = 0; j < 16; ++j) {
        int idx = base + j;
        if (idx < n) offs[idx] = acc;
        acc += v[j];
    }
    if (tid == 255) bsums[blockIdx.x] = tsum[255];
}

// --- K3b: add scanned block totals; emit final offs -------------------------
__global__ void k_scan_add(int* offs, const int* bsums, int n, int nblk) {
    __shared__ int carry_s;
    const int tid = threadIdx.x;
    const int b = blockIdx.x;
    if (tid == 0) {
        int c = 0;
        for (int i = 0; i < b; ++i) c += bsums[i];
        carry_s = c;
        if (b == nblk - 1) offs[n] = c + bsums[b];   // total == E
    }
    __syncthreads();
    const int carry = carry_s;
    const int base = b * CHUNK + tid * 16;
    for (int j = 0; j < 16; ++j) {
        int idx = base + j;
        if (idx < n) offs[idx] += carry;
    }
}

// --- K4: scatter edges into CSR buckets, XCD-partitioned, atomic-free -------
__global__ void k_scatter(const int* __restrict__ src, const int* __restrict__ dst,
                          const int* __restrict__ rank, const int* __restrict__ offs,
                          int* __restrict__ csr, int E, int nper) {
    const int pr = blockIdx.x & (NPART - 1);
    const int s  = blockIdx.x >> 3;
    const int lo = pr * nper;
    const int hi = lo + nper;
    const int base = s * SCHUNK;
    int end = base + SCHUNK;
    if (end > E) end = E;
    for (int i = base + (int)threadIdx.x; i < end; i += 256) {
        int d = dst[i];
        if (d >= lo && d < hi) {
            csr[offs[d] + rank[i]] = src[i];
        }
    }
}

// --- K5: gather-reduce mean aggregation, one wave per node ------------------
__global__ void k_aggregate(const void* feature, const u16* __restrict__ fcopy,
                            const int* offs, const int* csr, u16* agg,
                            const int* flag, int n, int npad) {
    int node = blockIdx.x * 4 + (threadIdx.x >> 6);
    int lane = threadIdx.x & 63;
    if (node >= npad) return;
    const int g = lane >> 4;       // edge sub-slot 0..3
    const int c = lane & 15;       // 16B chunk (8 bf16 cols) within row
    const u16* fb = flag[0] ? (const u16*)feature : fcopy;
    float acc[8];
    #pragma unroll
    for (int t = 0; t < 8; ++t) acc[t] = 0.f;
    int degn = 0;
    if (node < n) {
        int s = offs[node], e = offs[node + 1];
        degn = e - s;
        const uint4* fq = (const uint4*)fb;   // row = 16 uint4
        for (int j = s; j < e; j += 16) {
            int j0 = j + g, j1 = j0 + 4, j2 = j0 + 8, j3 = j0 + 12;
            uint4 u0 = {0,0,0,0}, u1 = {0,0,0,0}, u2 = {0,0,0,0}, u3 = {0,0,0,0};
            if (j0 < e) u0 = fq[(size_t)csr[j0] * 16 + c];
            if (j1 < e) u1 = fq[(size_t)csr[j1] * 16 + c];
            if (j2 < e) u2 = fq[(size_t)csr[j2] * 16 + c];
            if (j3 < e) u3 = fq[(size_t)csr[j3] * 16 + c];
            #define ACC8(U) \
                acc[0] += lo16(U.x); acc[1] += hi16(U.x); \
                acc[2] += lo16(U.y); acc[3] += hi16(U.y); \
                acc[4] += lo16(U.z); acc[5] += hi16(U.z); \
                acc[6] += lo16(U.w); acc[7] += hi16(U.w);
            ACC8(u0); ACC8(u1); ACC8(u2); ACC8(u3);
            #undef ACC8
        }
    }
    // combine the 4 edge-slot partials (lanes g=0..3 share chunk c)
    #pragma unroll
    for (int t = 0; t < 8; ++t) {
        acc[t] += __shfl_xor(acc[t], 16);
        acc[t] += __shfl_xor(acc[t], 32);
    }
    float sc = 1.0f / (float)(degn > 1 ? degn : 1);
    if (g == 0) {
        uint4 o4;
        o4.x = (u32)f2bf(acc[0] * sc) | ((u32)f2bf(acc[1] * sc) << 16);
        o4.y = (u32)f2bf(acc[2] * sc) | ((u32)f2bf(acc[3] * sc) << 16);
        o4.z = (u32)f2bf(acc[4] * sc) | ((u32)f2bf(acc[5] * sc) << 16);
        o4.w = (u32)f2bf(acc[6] * sc) | ((u32)f2bf(acc[7] * sc) << 16);
        ((uint4*)(agg + (size_t)node * D_DIM))[c] = o4;
    }
}

// --- K6: h = agg @ W^T + b via bf16 MFMA, prepacked W, h in place -----------
// 128 rows/block, 8 waves. After the MFMA section the 64KB sW LDS is dead;
// it is reused to reduce the 8 waves' BN partials in-block, so k_gemm emits
// ONE coalesced 256-float row per block (R4 post-mortem: per-WAVE rows made
// k_redstats walk 196 serial-latency loads -> 59.5us at 1% occupancy).
__global__ __launch_bounds__(512, 4)
void k_gemm(u16* __restrict__ agg, const u16* __restrict__ wpre,
            const void* __restrict__ bias, float* __restrict__ parts,
            const int* __restrict__ flag, int n) {
    __shared__ u16 sW[2 * 2048 * 8];          // 64 KB: plane0 | plane1
    const int tid = threadIdx.x;
    const int rb = blockIdx.x * 128;
    const int bf = flag[0];
    const int w = tid >> 6;
    const int lane = tid & 63;
    const int g = lane >> 4, c = lane & 15;

    // stage plane0 (+ plane1 if fp32 path): pure coalesced uint4 copy
    #pragma unroll
    for (int i = 0; i < 4; ++i) {
        int idx = i * 512 + tid;
        *(uint4*)(&sW[idx * 8]) = *(const uint4*)(wpre + (size_t)idx * 8);
    }
    if (!bf) {
        #pragma unroll
        for (int i = 0; i < 4; ++i) {
            int idx = i * 512 + tid;
            *(uint4*)(&sW[16384 + idx * 8]) =
                *(const uint4*)(wpre + 16384 + (size_t)idx * 8);
        }
    }

    // A fragments: 4 x 16B per lane, from global (rows written by k_aggregate)
    bf16x8 afr[4];
    {
        const u16* arow = agg + (size_t)(rb + w * 16 + c) * D_DIM + g * 8;
        #pragma unroll
        for (int kt = 0; kt < 4; ++kt)
            afr[kt] = *(const bf16x8*)(arow + kt * 32);
    }

    f32x4 acc[8];
    #pragma unroll
    for (int ot = 0; ot < 8; ++ot) acc[ot] = (f32x4){0.f, 0.f, 0.f, 0.f};

    __syncthreads();
    #pragma unroll
    for (int ot = 0; ot < 8; ++ot) {
        #pragma unroll
        for (int kt = 0; kt < 4; ++kt) {
            bf16x8 bfr = *(const bf16x8*)(&sW[((ot * 4 + kt) * 64 + lane) * 8]);
            acc[ot] = __builtin_amdgcn_mfma_f32_16x16x32_bf16(
                afr[kt], bfr, acc[ot], 0, 0, 0);
        }
    }
    if (!bf) {                                 // residual plane, same acc
        #pragma unroll
        for (int ot = 0; ot < 8; ++ot) {
            #pragma unroll
            for (int kt = 0; kt < 4; ++kt) {
                bf16x8 bfr = *(const bf16x8*)(
                    &sW[16384 + ((ot * 4 + kt) * 64 + lane) * 8]);
                acc[ot] = __builtin_amdgcn_mfma_f32_16x16x32_bf16(
                    afr[kt], bfr, acc[ot], 0, 0, 0);
            }
        }
    }

    // sW is dead from here on: reuse as float scratch for BN partials
    float* red = (float*)sW;                   // [8][256] floats = 8 KB
    __syncthreads();                           // all waves done reading sW

    // Epilogue: bias, BN partials (rows<n only), packed bf16 store.
    // D layout: col = ot*16 + c, row = rowbase + r.
    const int rowbase = rb + w * 16 + g * 4;
    #pragma unroll
    for (int ot = 0; ot < 8; ++ot) {
        const int o = ot * 16 + c;
        float bv = bf ? bf2f(((const u16*)bias)[o]) : ((const float*)bias)[o];
        float s = 0.f, q = 0.f;
        float hv[4];
        #pragma unroll
        for (int r = 0; r < 4; ++r) {
            float h = acc[ot][r] + bv;
            hv[r] = h;
            if (rowbase + r < n) { s += h; q += h * h; }
        }
        #pragma unroll
        for (int r = 0; r < 4; ++r) {
            float hp = __shfl_xor(hv[r], 1);       // neighbor col (o^1)
            if (!(lane & 1)) {
                u32 pk = (u32)f2bf(hv[r]) | ((u32)f2bf(hp) << 16);
                *(u32*)(agg + (size_t)(rowbase + r) * D_DIM + o) = pk;
            }
        }
        s += __shfl_xor(s, 16); s += __shfl_xor(s, 32);
        q += __shfl_xor(q, 16); q += __shfl_xor(q, 32);
        if (g == 0) { red[w * 256 + o] = s; red[w * 256 + 128 + o] = q; }
    }
    __syncthreads();
    if (tid < 256) {                            // cross-wave reduce, one row/block
        float a = 0.f;
        #pragma unroll
        for (int ww = 0; ww < 8; ++ww) a += red[ww * 256 + tid];
        parts[(size_t)blockIdx.x * 256 + tid] = a;
    }
}

// --- K6b: reduce per-block BN partials into stats ---------------------------
// 8 independent accumulators (static-indexed): 8 loads in flight per step
// instead of R4's single dependent chain (196 serial latencies = 59.5us).
__global__ void k_redstats(const float* __restrict__ partials,
                           float* __restrict__ stats, int nb) {
    const int tid = threadIdx.x;
    float a0 = 0.f, a1 = 0.f, a2 = 0.f, a3 = 0.f;
    float a4 = 0.f, a5 = 0.f, a6 = 0.f, a7 = 0.f;
    for (int r0 = blockIdx.x * 8; r0 < nb; r0 += gridDim.x * 8) {
        if (r0 + 0 < nb) a0 += partials[(size_t)(r0 + 0) * 256 + tid];
        if (r0 + 1 < nb) a1 += partials[(size_t)(r0 + 1) * 256 + tid];
        if (r0 + 2 < nb) a2 += partials[(size_t)(r0 + 2) * 256 + tid];
        if (r0 + 3 < nb) a3 += partials[(size_t)(r0 + 3) * 256 + tid];
        if (r0 + 4 < nb) a4 += partials[(size_t)(r0 + 4) * 256 + tid];
        if (r0 + 5 < nb) a5 += partials[(size_t)(r0 + 5) * 256 + tid];
        if (r0 + 6 < nb) a6 += partials[(size_t)(r0 + 6) * 256 + tid];
        if (r0 + 7 < nb) a7 += partials[(size_t)(r0 + 7) * 256 + tid];
    }
    float s = ((a0 + a1) + (a2 + a3)) + ((a4 + a5) + (a6 + a7));
    atomicAdd(&stats[tid], s);
}

// --- K8: out = feature + relu(h*scale + shift); BN finalize folded in -------
__global__ void k_apply(const u16* h, const void* feature, const float* stats,
                        const void* gamma, const void* beta, void* outp,
                        const int* flag, int total8, float invn) {
    __shared__ float ssc[128], ssh[128];
    int tid = threadIdx.x;
    int bf = flag[0];
    if (tid < 128) {
        float mean = stats[tid] * invn;
        float var = stats[128 + tid] * invn - mean * mean;
        var = fmaxf(var, 0.f);
        float inv = rsqrtf(var + 1e-5f);
        float g = bf ? bf2f(((const u16*)gamma)[tid]) : ((const float*)gamma)[tid];
        float bb = bf ? bf2f(((const u16*)beta)[tid]) : ((const float*)beta)[tid];
        float sc = inv * g;
        ssc[tid] = sc;
        ssh[tid] = bb - mean * sc;
    }
    __syncthreads();
    int i = blockIdx.x * 256 + tid;
    if (i >= total8) return;
    size_t base = (size_t)i * 8;
    int c0 = (int)(base & (D_DIM - 1));
    uint4 h4 = ((const uint4*)h)[i];
    u32 hw[4] = {h4.x, h4.y, h4.z, h4.w};
    float hv[8];
    for (int j = 0; j < 4; ++j) { hv[2*j] = lo16(hw[j]); hv[2*j+1] = hi16(hw[j]); }
    float fv[8];
    if (bf) {
        uint4 f4 = ((const uint4*)feature)[i];
        u32 fw[4] = {f4.x, f4.y, f4.z, f4.w};
        for (int j = 0; j < 4; ++j) { fv[2*j] = lo16(fw[j]); fv[2*j+1] = hi16(fw[j]); }
    } else {
        float4 fa = ((const float4*)feature)[i * 2];
        float4 fb = ((const float4*)feature)[i * 2 + 1];
        fv[0]=fa.x; fv[1]=fa.y; fv[2]=fa.z; fv[3]=fa.w;
        fv[4]=fb.x; fv[5]=fb.y; fv[6]=fb.z; fv[7]=fb.w;
    }
    float ov[8];
    for (int j = 0; j < 8; ++j)
        ov[j] = fmaxf(hv[j] * ssc[c0 + j] + ssh[c0 + j], 0.f) + fv[j];
    if (bf) {
        uint4 o4;
        u32 ow[4];
        for (int j = 0; j < 4; ++j)
            ow[j] = (u32)f2bf(ov[2*j]) | ((u32)f2bf(ov[2*j+1]) << 16);
        o4.x = ow[0]; o4.y = ow[1]; o4.z = ow[2]; o4.w = ow[3];
        ((uint4*)outp)[i] = o4;
    } else {
        float4 oa, ob;
        oa.x=ov[0]; oa.y=ov[1]; oa.z=ov[2]; oa.w=ov[3];
        ob.x=ov[4]; ob.y=ov[5]; ob.z=ov[6]; ob.w=ov[7];
        ((float4*)outp)[i * 2] = oa;
        ((float4*)outp)[i * 2 + 1] = ob;
    }
}

static inline size_t al256s(size_t x) { return (x + 255) & ~(size_t)255; }
static inline int gmax1(int x) { return x > 0 ? x : 1; }

extern "C" void kernel_launch(void* const* d_in, const int* in_sizes, int n_in,
                              void* d_out, int out_size, void* d_ws, size_t ws_size,
                              hipStream_t stream) {
    const void* feature = d_in[0];
    const int*  src     = (const int*)d_in[1];
    const int*  dst     = (const int*)d_in[2];
    const void* W       = d_in[3];
    const void* bias    = d_in[4];
    const void* gamma   = d_in[5];
    const void* beta    = d_in[6];

    const int N = in_sizes[0] / D_DIM;
    const int E = in_sizes[1];
    const int Npad = (N + 127) & ~127;             // 128-row gemm blocks
    const int nblk = (N + CHUNK - 1) / CHUNK;      // scan blocks
    const int nper = (N + NPART - 1) / NPART;      // nodes per XCD partition
    const int gb   = Npad / 128;                   // gemm blocks == partial rows

    char* p = (char*)d_ws;
    size_t o = 0;
    int*   flag   = (int*)(p + o);      o += 256;
    int*   deg    = (int*)(p + o);      o += (size_t)N * 4;
    float* stats  = (float*)(p + o);    o += 256 * 4;           // sum[128],sq[128]
    const int zero_words = N + 256;                              // deg+stats contiguous
    o = al256s(o);
    u16*   wpre   = (u16*)(p + o);      o += al256s(2 * 16384 * 2);  // 2 bf16 planes
    int*   bsums  = (int*)(p + o);      o += al256s(((size_t)nblk + 8) * 4);
    int*   offs   = (int*)(p + o);      o += al256s(((size_t)N + 8) * 4);
    int*   csr    = (int*)(p + o);      o += al256s((size_t)E * 4);
    float* parts  = (float*)(p + o);    o += al256s((size_t)gb * 256 * 4);
    u16*   agg    = (u16*)(p + o);      o += al256s((size_t)Npad * D_DIM * 2);
    int*   rank   = (int*)agg;   // aliased: rank (E ints) dies before k_aggregate
                                 // writes agg; Npad*256B >= E*4B here
    u16*   fbf    = (u16*)d_out; // bf16 feature copy; dead before k_apply writes
    (void)ws_size; (void)n_in; (void)out_size;

    int eb = gmax1((E + 255) / 256);
    int total8 = N * D_DIM / 8;
    int sblocks = gmax1(((E + SCHUNK - 1) / SCHUNK) * NPART);

    GCNLayer_76647986365164_kernel<<<gmax1((zero_words + 255) / 256), 256, 0, stream>>>(
        deg, zero_words, (const u32*)feature, flag);
    k_tobf<<<gmax1((total8 + 255) / 256) + 1, 256, 0, stream>>>(
        (const float*)feature, fbf, W, wpre, flag, total8);
    k_deg<<<eb, 256, 0, stream>>>(dst, deg, rank, E);
    k_scan_local<<<gmax1(nblk), 256, 0, stream>>>(deg, offs, bsums, N);
    k_scan_add<<<gmax1(nblk), 256, 0, stream>>>(offs, bsums, N, nblk);
    k_scatter<<<sblocks, 256, 0, stream>>>(src, dst, rank, offs, csr, E, nper);
    k_aggregate<<<gmax1(Npad / 4), 256, 0, stream>>>(
        feature, fbf, offs, csr, agg, flag, N, Npad);
    k_gemm<<<gmax1(gb), 512, 0, stream>>>(agg, wpre, bias, parts, flag, N);
    k_redstats<<<32, 256, 0, stream>>>(parts, stats, gb);
    k_apply<<<gmax1((total8 + 255) / 256), 256, 0, stream>>>(
        agg, feature, stats, gamma, beta, d_out, flag, total8, 1.0f / (float)N);
}

// Round 6
// 284.839 us; speedup vs baseline: 1.1714x; 1.0349x over previous
//
#include <hip/hip_runtime.h>

typedef unsigned short u16;
typedef unsigned int u32;

#define D_DIM 128
#define CHUNK 4096    // elements scanned per block (256 threads x 16)
#define SCHUNK 4096   // edges per scatter stripe
#define NPART 8       // XCD count

typedef __attribute__((ext_vector_type(8))) short bf16x8;
typedef __attribute__((ext_vector_type(4))) float f32x4;

__device__ __forceinline__ float bf2f(u16 h) {
    u32 u = ((u32)h) << 16;
    return __uint_as_float(u);
}
__device__ __forceinline__ u16 f2bf(float f) {
    u32 u = __float_as_uint(f);
    u32 r = (u >> 16) & 1u;
    u += 0x7fffu + r;                 // round-to-nearest-even
    return (u16)(u >> 16);
}
__device__ __forceinline__ float lo16(u32 u) { return bf2f((u16)(u & 0xffffu)); }
__device__ __forceinline__ float hi16(u32 u) { return bf2f((u16)(u >> 16)); }

// --- K1: zero scratch words + dtype detect (merged; harness symbol kept) ----
__global__ void GCNLayer_76647986365164_kernel(int* p, int nwords,
                                               const u32* w, int* flag) {
    int i = blockIdx.x * blockDim.x + threadIdx.x;
    if (i < nwords) p[i] = 0;
    if (blockIdx.x == 0) {
        __shared__ int cnt;
        if (threadIdx.x == 0) cnt = 0;
        __syncthreads();
        int c = 0;
        for (int j = 0; j < 4; ++j) {
            u32 x = w[threadIdx.x * 4 + j];
            u32 e = (x >> 7) & 0xFFu;
            if (e >= 100u && e <= 140u) c++;
        }
        atomicAdd(&cnt, c);
        __syncthreads();
        if (threadIdx.x == 0) flag[0] = (cnt >= 700) ? 1 : 0;
    }
}

// --- K1b: fp32 feature -> bf16 copy, and (last block) W prepack -------------
__global__ void k_tobf(const float* __restrict__ f, u16* __restrict__ fb,
                       const void* __restrict__ W, u16* __restrict__ wpre,
                       const int* __restrict__ flag, int total8) {
    const int bf = flag[0];
    if (blockIdx.x == gridDim.x - 1) {          // W prepack block
        const int tid = threadIdx.x;
        #pragma unroll
        for (int i = 0; i < 8; ++i) {
            int idx = i * 256 + tid;            // 2048 fragment units
            int frag = idx >> 6, dl = idx & 63;
            int ot = frag >> 2, kt = frag & 3;
            int dg = dl >> 4, dc = dl & 15;
            int row = ot * 16 + dc, col = kt * 32 + dg * 8;
            if (bf) {
                *(uint4*)(wpre + (size_t)idx * 8) =
                    *(const uint4*)((const u16*)W + row * 128 + col);
            } else {
                const float* Wf = (const float*)W;
                float4 x = *(const float4*)(Wf + row * 128 + col);
                float4 y = *(const float4*)(Wf + row * 128 + col + 4);
                float v[8] = {x.x, x.y, x.z, x.w, y.x, y.y, y.z, y.w};
                u16 h0[8], h1[8];
                #pragma unroll
                for (int j = 0; j < 8; ++j) {
                    h0[j] = f2bf(v[j]);
                    h1[j] = f2bf(v[j] - bf2f(h0[j]));   // residual plane
                }
                uint4 p0, p1;
                p0.x = (u32)h0[0] | ((u32)h0[1] << 16);
                p0.y = (u32)h0[2] | ((u32)h0[3] << 16);
                p0.z = (u32)h0[4] | ((u32)h0[5] << 16);
                p0.w = (u32)h0[6] | ((u32)h0[7] << 16);
                p1.x = (u32)h1[0] | ((u32)h1[1] << 16);
                p1.y = (u32)h1[2] | ((u32)h1[3] << 16);
                p1.z = (u32)h1[4] | ((u32)h1[5] << 16);
                p1.w = (u32)h1[6] | ((u32)h1[7] << 16);
                *(uint4*)(wpre + (size_t)idx * 8) = p0;
                *(uint4*)(wpre + 16384 + (size_t)idx * 8) = p1;
            }
        }
        return;
    }
    if (bf) return;                  // input already bf16, no feature copy
    int i = blockIdx.x * 256 + threadIdx.x;
    if (i >= total8) return;
    float4 a = ((const float4*)f)[i * 2];
    float4 b = ((const float4*)f)[i * 2 + 1];
    uint4 o;
    o.x = (u32)f2bf(a.x) | ((u32)f2bf(a.y) << 16);
    o.y = (u32)f2bf(a.z) | ((u32)f2bf(a.w) << 16);
    o.z = (u32)f2bf(b.x) | ((u32)f2bf(b.y) << 16);
    o.w = (u32)f2bf(b.z) | ((u32)f2bf(b.w) << 16);
    ((uint4*)fb)[i] = o;
}

// --- K2: in-degree count + per-edge bucket rank -----------------------------
__global__ void k_deg(const int* __restrict__ dst, int* __restrict__ deg,
                      int* __restrict__ rank, int E) {
    int i = blockIdx.x * blockDim.x + threadIdx.x;
    if (i < E) rank[i] = atomicAdd(&deg[dst[i]], 1);
}

// --- K3a: block-local exclusive scan (multi-block; LDS Hillis-Steele) -------
__global__ void k_scan_local(const int* deg, int* offs, int* bsums, int n) {
    __shared__ int tsum[256];
    const int tid = threadIdx.x;
    const int base = blockIdx.x * CHUNK + tid * 16;
    int v[16];
    int run = 0;
    for (int j = 0; j < 16; ++j) {
        int idx = base + j;
        v[j] = (idx < n) ? deg[idx] : 0;
        run += v[j];
    }
    tsum[tid] = run;
    __syncthreads();
    for (int off = 1; off < 256; off <<= 1) {      // inclusive scan of thread sums
        int val = tsum[tid];
        int add = (tid >= off) ? tsum[tid - off] : 0;
        __syncthreads();
        tsum[tid] = val + add;
        __syncthreads();
    }
    int acc = tsum[tid] - run;                     // exclusive start (local)
    for (int j = 0; j < 16; ++j) {
        int idx = base + j;
        if (idx < n) offs[idx] = acc;
        acc += v[j];
    }
    if (tid == 255) bsums[blockIdx.x] = tsum[255];
}

// --- K3b: add scanned block totals; emit final offs -------------------------
__global__ void k_scan_add(int* offs, const int* bsums, int n, int nblk) {
    __shared__ int carry_s;
    const int tid = threadIdx.x;
    const int b = blockIdx.x;
    if (tid == 0) {
        int c = 0;
        for (int i = 0; i < b; ++i) c += bsums[i];
        carry_s = c;
        if (b == nblk - 1) offs[n] = c + bsums[b];   // total == E
    }
    __syncthreads();
    const int carry = carry_s;
    const int base = b * CHUNK + tid * 16;
    for (int j = 0; j < 16; ++j) {
        int idx = base + j;
        if (idx < n) offs[idx] += carry;
    }
}

// --- K4: scatter edges into CSR buckets, XCD-partitioned, atomic-free -------
__global__ void k_scatter(const int* __restrict__ src, const int* __restrict__ dst,
                          const int* __restrict__ rank, const int* __restrict__ offs,
                          int* __restrict__ csr, int E, int nper) {
    const int pr = blockIdx.x & (NPART - 1);
    const int s  = blockIdx.x >> 3;
    const int lo = pr * nper;
    const int hi = lo + nper;
    const int base = s * SCHUNK;
    int end = base + SCHUNK;
    if (end > E) end = E;
    for (int i = base + (int)threadIdx.x; i < end; i += 256) {
        int d = dst[i];
        if (d >= lo && d < hi) {
            csr[offs[d] + rank[i]] = src[i];
        }
    }
}

// --- K5: gather-reduce mean aggregation, 16 LANES PER NODE ------------------
// R5 post-mortem: the 1-node-per-wave scheme was issue-bound, not BW-bound
// (VALUBusy 65% while arithmetic floor is ~3us): ~300 insts of per-wave
// overhead (shfl-combine epilogue, predication, addressing) per ~10 edges of
// work, x100K waves. New layout: lane c in [0,16) permanently owns 16B of the
// row; 4 nodes/wave, 16 nodes/block. NO cross-lane combine at all; 4-deep
// unrolled edge loop gives 16 independent 256B gathers in flight per wave
// (vs 4). Same memory traffic (FETCH ~113MB), 4x fewer waves.
__global__ void k_aggregate(const void* feature, const u16* __restrict__ fcopy,
                            const int* offs, const int* csr, u16* agg,
                            const int* flag, int n, int npad) {
    const int tid = threadIdx.x;
    const int node = blockIdx.x * 16 + (tid >> 4);
    const int c = tid & 15;        // 16B chunk (8 bf16 cols) within row
    if (node >= npad) return;
    const u16* fb = flag[0] ? (const u16*)feature : fcopy;
    const uint4* fq = (const uint4*)fb;   // row = 16 uint4
    float acc[8];
    #pragma unroll
    for (int t = 0; t < 8; ++t) acc[t] = 0.f;
    int degn = 0;
    if (node < n) {
        int s = offs[node], e = offs[node + 1];
        degn = e - s;
        for (int j = s; j < e; j += 4) {
            int j1 = j + 1, j2 = j + 2, j3 = j + 3;
            uint4 u0 = {0,0,0,0}, u1 = {0,0,0,0}, u2 = {0,0,0,0}, u3 = {0,0,0,0};
            u0 = fq[(size_t)csr[j] * 16 + c];                  // j<e by loop cond
            if (j1 < e) u1 = fq[(size_t)csr[j1] * 16 + c];
            if (j2 < e) u2 = fq[(size_t)csr[j2] * 16 + c];
            if (j3 < e) u3 = fq[(size_t)csr[j3] * 16 + c];
            #define ACC8(U) \
                acc[0] += lo16(U.x); acc[1] += hi16(U.x); \
                acc[2] += lo16(U.y); acc[3] += hi16(U.y); \
                acc[4] += lo16(U.z); acc[5] += hi16(U.z); \
                acc[6] += lo16(U.w); acc[7] += hi16(U.w);
            ACC8(u0); ACC8(u1); ACC8(u2); ACC8(u3);
            #undef ACC8
        }
    }
    float sc = 1.0f / (float)(degn > 1 ? degn : 1);
    uint4 o4;
    o4.x = (u32)f2bf(acc[0] * sc) | ((u32)f2bf(acc[1] * sc) << 16);
    o4.y = (u32)f2bf(acc[2] * sc) | ((u32)f2bf(acc[3] * sc) << 16);
    o4.z = (u32)f2bf(acc[4] * sc) | ((u32)f2bf(acc[5] * sc) << 16);
    o4.w = (u32)f2bf(acc[6] * sc) | ((u32)f2bf(acc[7] * sc) << 16);
    ((uint4*)(agg + (size_t)node * D_DIM))[c] = o4;
}

// --- K6: h = agg @ W^T + b via bf16 MFMA, prepacked W, h in place -----------
// 128 rows/block, 8 waves. After the MFMA section the 64KB sW LDS is dead;
// it is reused to reduce the 8 waves' BN partials in-block, so k_gemm emits
// ONE coalesced 256-float row per block.
__global__ __launch_bounds__(512, 4)
void k_gemm(u16* __restrict__ agg, const u16* __restrict__ wpre,
            const void* __restrict__ bias, float* __restrict__ parts,
            const int* __restrict__ flag, int n) {
    __shared__ u16 sW[2 * 2048 * 8];          // 64 KB: plane0 | plane1
    const int tid = threadIdx.x;
    const int rb = blockIdx.x * 128;
    const int bf = flag[0];
    const int w = tid >> 6;
    const int lane = tid & 63;
    const int g = lane >> 4, c = lane & 15;

    // stage plane0 (+ plane1 if fp32 path): pure coalesced uint4 copy
    #pragma unroll
    for (int i = 0; i < 4; ++i) {
        int idx = i * 512 + tid;
        *(uint4*)(&sW[idx * 8]) = *(const uint4*)(wpre + (size_t)idx * 8);
    }
    if (!bf) {
        #pragma unroll
        for (int i = 0; i < 4; ++i) {
            int idx = i * 512 + tid;
            *(uint4*)(&sW[16384 + idx * 8]) =
                *(const uint4*)(wpre + 16384 + (size_t)idx * 8);
        }
    }

    // A fragments: 4 x 16B per lane, from global (rows written by k_aggregate)
    bf16x8 afr[4];
    {
        const u16* arow = agg + (size_t)(rb + w * 16 + c) * D_DIM + g * 8;
        #pragma unroll
        for (int kt = 0; kt < 4; ++kt)
            afr[kt] = *(const bf16x8*)(arow + kt * 32);
    }

    f32x4 acc[8];
    #pragma unroll
    for (int ot = 0; ot < 8; ++ot) acc[ot] = (f32x4){0.f, 0.f, 0.f, 0.f};

    __syncthreads();
    #pragma unroll
    for (int ot = 0; ot < 8; ++ot) {
        #pragma unroll
        for (int kt = 0; kt < 4; ++kt) {
            bf16x8 bfr = *(const bf16x8*)(&sW[((ot * 4 + kt) * 64 + lane) * 8]);
            acc[ot] = __builtin_amdgcn_mfma_f32_16x16x32_bf16(
                afr[kt], bfr, acc[ot], 0, 0, 0);
        }
    }
    if (!bf) {                                 // residual plane, same acc
        #pragma unroll
        for (int ot = 0; ot < 8; ++ot) {
            #pragma unroll
            for (int kt = 0; kt < 4; ++kt) {
                bf16x8 bfr = *(const bf16x8*)(
                    &sW[16384 + ((ot * 4 + kt) * 64 + lane) * 8]);
                acc[ot] = __builtin_amdgcn_mfma_f32_16x16x32_bf16(
                    afr[kt], bfr, acc[ot], 0, 0, 0);
            }
        }
    }

    // sW is dead from here on: reuse as float scratch for BN partials
    float* red = (float*)sW;                   // [8][256] floats = 8 KB
    __syncthreads();                           // all waves done reading sW

    // Epilogue: bias, BN partials (rows<n only), packed bf16 store.
    // D layout: col = ot*16 + c, row = rowbase + r.
    const int rowbase = rb + w * 16 + g * 4;
    #pragma unroll
    for (int ot = 0; ot < 8; ++ot) {
        const int o = ot * 16 + c;
        float bv = bf ? bf2f(((const u16*)bias)[o]) : ((const float*)bias)[o];
        float s = 0.f, q = 0.f;
        float hv[4];
        #pragma unroll
        for (int r = 0; r < 4; ++r) {
            float h = acc[ot][r] + bv;
            hv[r] = h;
            if (rowbase + r < n) { s += h; q += h * h; }
        }
        #pragma unroll
        for (int r = 0; r < 4; ++r) {
            float hp = __shfl_xor(hv[r], 1);       // neighbor col (o^1)
            if (!(lane & 1)) {
                u32 pk = (u32)f2bf(hv[r]) | ((u32)f2bf(hp) << 16);
                *(u32*)(agg + (size_t)(rowbase + r) * D_DIM + o) = pk;
            }
        }
        s += __shfl_xor(s, 16); s += __shfl_xor(s, 32);
        q += __shfl_xor(q, 16); q += __shfl_xor(q, 32);
        if (g == 0) { red[w * 256 + o] = s; red[w * 256 + 128 + o] = q; }
    }
    __syncthreads();
    if (tid < 256) {                            // cross-wave reduce, one row/block
        float a = 0.f;
        #pragma unroll
        for (int ww = 0; ww < 8; ++ww) a += red[ww * 256 + tid];
        parts[(size_t)blockIdx.x * 256 + tid] = a;
    }
}

// --- K6b: reduce per-block BN partials into stats ---------------------------
// 8 independent accumulators: 8 loads in flight per step.
__global__ void k_redstats(const float* __restrict__ partials,
                           float* __restrict__ stats, int nb) {
    const int tid = threadIdx.x;
    float a0 = 0.f, a1 = 0.f, a2 = 0.f, a3 = 0.f;
    float a4 = 0.f, a5 = 0.f, a6 = 0.f, a7 = 0.f;
    for (int r0 = blockIdx.x * 8; r0 < nb; r0 += gridDim.x * 8) {
        if (r0 + 0 < nb) a0 += partials[(size_t)(r0 + 0) * 256 + tid];
        if (r0 + 1 < nb) a1 += partials[(size_t)(r0 + 1) * 256 + tid];
        if (r0 + 2 < nb) a2 += partials[(size_t)(r0 + 2) * 256 + tid];
        if (r0 + 3 < nb) a3 += partials[(size_t)(r0 + 3) * 256 + tid];
        if (r0 + 4 < nb) a4 += partials[(size_t)(r0 + 4) * 256 + tid];
        if (r0 + 5 < nb) a5 += partials[(size_t)(r0 + 5) * 256 + tid];
        if (r0 + 6 < nb) a6 += partials[(size_t)(r0 + 6) * 256 + tid];
        if (r0 + 7 < nb) a7 += partials[(size_t)(r0 + 7) * 256 + tid];
    }
    float s = ((a0 + a1) + (a2 + a3)) + ((a4 + a5) + (a6 + a7));
    atomicAdd(&stats[tid], s);
}

// --- K8: out = feature + relu(h*scale + shift); BN finalize folded in -------
__global__ void k_apply(const u16* h, const void* feature, const float* stats,
                        const void* gamma, const void* beta, void* outp,
                        const int* flag, int total8, float invn) {
    __shared__ float ssc[128], ssh[128];
    int tid = threadIdx.x;
    int bf = flag[0];
    if (tid < 128) {
        float mean = stats[tid] * invn;
        float var = stats[128 + tid] * invn - mean * mean;
        var = fmaxf(var, 0.f);
        float inv = rsqrtf(var + 1e-5f);
        float g = bf ? bf2f(((const u16*)gamma)[tid]) : ((const float*)gamma)[tid];
        float bb = bf ? bf2f(((const u16*)beta)[tid]) : ((const float*)beta)[tid];
        float sc = inv * g;
        ssc[tid] = sc;
        ssh[tid] = bb - mean * sc;
    }
    __syncthreads();
    int i = blockIdx.x * 256 + tid;
    if (i >= total8) return;
    size_t base = (size_t)i * 8;
    int c0 = (int)(base & (D_DIM - 1));
    uint4 h4 = ((const uint4*)h)[i];
    u32 hw[4] = {h4.x, h4.y, h4.z, h4.w};
    float hv[8];
    for (int j = 0; j < 4; ++j) { hv[2*j] = lo16(hw[j]); hv[2*j+1] = hi16(hw[j]); }
    float fv[8];
    if (bf) {
        uint4 f4 = ((const uint4*)feature)[i];
        u32 fw[4] = {f4.x, f4.y, f4.z, f4.w};
        for (int j = 0; j < 4; ++j) { fv[2*j] = lo16(fw[j]); fv[2*j+1] = hi16(fw[j]); }
    } else {
        float4 fa = ((const float4*)feature)[i * 2];
        float4 fb = ((const float4*)feature)[i * 2 + 1];
        fv[0]=fa.x; fv[1]=fa.y; fv[2]=fa.z; fv[3]=fa.w;
        fv[4]=fb.x; fv[5]=fb.y; fv[6]=fb.z; fv[7]=fb.w;
    }
    float ov[8];
    for (int j = 0; j < 8; ++j)
        ov[j] = fmaxf(hv[j] * ssc[c0 + j] + ssh[c0 + j], 0.f) + fv[j];
    if (bf) {
        uint4 o4;
        u32 ow[4];
        for (int j = 0; j < 4; ++j)
            ow[j] = (u32)f2bf(ov[2*j]) | ((u32)f2bf(ov[2*j+1]) << 16);
        o4.x = ow[0]; o4.y = ow[1]; o4.z = ow[2]; o4.w = ow[3];
        ((uint4*)outp)[i] = o4;
    } else {
        float4 oa, ob;
        oa.x=ov[0]; oa.y=ov[1]; oa.z=ov[2]; oa.w=ov[3];
        ob.x=ov[4]; ob.y=ov[5]; ob.z=ov[6]; ob.w=ov[7];
        ((float4*)outp)[i * 2] = oa;
        ((float4*)outp)[i * 2 + 1] = ob;
    }
}

static inline size_t al256s(size_t x) { return (x + 255) & ~(size_t)255; }
static inline int gmax1(int x) { return x > 0 ? x : 1; }

extern "C" void kernel_launch(void* const* d_in, const int* in_sizes, int n_in,
                              void* d_out, int out_size, void* d_ws, size_t ws_size,
                              hipStream_t stream) {
    const void* feature = d_in[0];
    const int*  src     = (const int*)d_in[1];
    const int*  dst     = (const int*)d_in[2];
    const void* W       = d_in[3];
    const void* bias    = d_in[4];
    const void* gamma   = d_in[5];
    const void* beta    = d_in[6];

    const int N = in_sizes[0] / D_DIM;
    const int E = in_sizes[1];
    const int Npad = (N + 127) & ~127;             // 128-row gemm blocks
    const int nblk = (N + CHUNK - 1) / CHUNK;      // scan blocks
    const int nper = (N + NPART - 1) / NPART;      // nodes per XCD partition
    const int gb   = Npad / 128;                   // gemm blocks == partial rows

    char* p = (char*)d_ws;
    size_t o = 0;
    int*   flag   = (int*)(p + o);      o += 256;
    int*   deg    = (int*)(p + o);      o += (size_t)N * 4;
    float* stats  = (float*)(p + o);    o += 256 * 4;           // sum[128],sq[128]
    const int zero_words = N + 256;                              // deg+stats contiguous
    o = al256s(o);
    u16*   wpre   = (u16*)(p + o);      o += al256s(2 * 16384 * 2);  // 2 bf16 planes
    int*   bsums  = (int*)(p + o);      o += al256s(((size_t)nblk + 8) * 4);
    int*   offs   = (int*)(p + o);      o += al256s(((size_t)N + 8) * 4);
    int*   csr    = (int*)(p + o);      o += al256s((size_t)E * 4);
    float* parts  = (float*)(p + o);    o += al256s((size_t)gb * 256 * 4);
    u16*   agg    = (u16*)(p + o);      o += al256s((size_t)Npad * D_DIM * 2);
    int*   rank   = (int*)agg;   // aliased: rank (E ints) dies before k_aggregate
                                 // writes agg; Npad*256B >= E*4B here
    u16*   fbf    = (u16*)d_out; // bf16 feature copy; dead before k_apply writes
    (void)ws_size; (void)n_in; (void)out_size;

    int eb = gmax1((E + 255) / 256);
    int total8 = N * D_DIM / 8;
    int sblocks = gmax1(((E + SCHUNK - 1) / SCHUNK) * NPART);

    GCNLayer_76647986365164_kernel<<<gmax1((zero_words + 255) / 256), 256, 0, stream>>>(
        deg, zero_words, (const u32*)feature, flag);
    k_tobf<<<gmax1((total8 + 255) / 256) + 1, 256, 0, stream>>>(
        (const float*)feature, fbf, W, wpre, flag, total8);
    k_deg<<<eb, 256, 0, stream>>>(dst, deg, rank, E);
    k_scan_local<<<gmax1(nblk), 256, 0, stream>>>(deg, offs, bsums, N);
    k_scan_add<<<gmax1(nblk), 256, 0, stream>>>(offs, bsums, N, nblk);
    k_scatter<<<sblocks, 256, 0, stream>>>(src, dst, rank, offs, csr, E, nper);
    k_aggregate<<<gmax1(Npad / 16), 256, 0, stream>>>(
        feature, fbf, offs, csr, agg, flag, N, Npad);
    k_gemm<<<gmax1(gb), 512, 0, stream>>>(agg, wpre, bias, parts, flag, N);
    k_redstats<<<32, 256, 0, stream>>>(parts, stats, gb);
    k_apply<<<gmax1((total8 + 255) / 256), 256, 0, stream>>>(
        agg, feature, stats, gamma, beta, d_out, flag, total8, 1.0f / (float)N);
}